// Round 1
// baseline (188.655 us; speedup 1.0000x reference)
//
#include <hip/hip_runtime.h>

#define BATCH 262144
#define NI 9
#define NH 100
#define NO 2
#define T 25
#define BETA 0.95f
#define THR 1.0f

// One thread per batch element.
// Phase 1: cur1[h] = x·W1[h,:] + b1[h] computed per h (scalar), 25-step LIF
//          recurrence run immediately with scalar mem1; each step's spike
//          conditionally accumulates W2[:,h] into per-step acc[25] (float2-ish).
//          Uses reset[t] == spk[t-1] so only ONE compare per step.
// Phase 2: 25-step output LIF on the accumulated currents, write spk2/mem2.
__global__ __launch_bounds__(256) void snn_fwd(
    const float* __restrict__ x,
    const float* __restrict__ W1,
    const float* __restrict__ b1,
    const float* __restrict__ W2,
    const float* __restrict__ b2,
    float* __restrict__ out)
{
    const int b = blockIdx.x * blockDim.x + threadIdx.x;
    if (b >= BATCH) return;

    // x row: 9 consecutive floats per thread (36 B) — cache lines fully used.
    float xi[NI];
#pragma unroll
    for (int i = 0; i < NI; ++i) xi[i] = x[(size_t)b * NI + i];

    // Per-timestep accumulated layer-2 currents (without bias).
    float acc0[T], acc1[T];
#pragma unroll
    for (int t = 0; t < T; ++t) { acc0[t] = 0.0f; acc1[t] = 0.0f; }

    for (int h = 0; h < NH; ++h) {
        // cur1 = dot(x, W1[h,:]) + b1[h]  (W1/b1 accesses are wave-uniform -> s_load)
        float c = xi[0] * W1[h * NI];
#pragma unroll
        for (int i = 1; i < NI; ++i) c = fmaf(xi[i], W1[h * NI + i], c);
        c += b1[h];

        const float w0 = W2[h];        // W2[0, h]
        const float w1 = W2[NH + h];   // W2[1, h]

        float mem = 0.0f, spk = 0.0f;  // spk doubles as next step's reset
#pragma unroll
        for (int t = 0; t < T; ++t) {
            mem = fmaf(BETA, mem, c) - spk;      // beta*mem + cur1 - reset*THR
            spk = (mem > THR) ? 1.0f : 0.0f;     // spike(mem - 1) ; exact equiv.
            acc0[t] = fmaf(spk, w0, acc0[t]);
            acc1[t] = fmaf(spk, w1, acc1[t]);
        }
    }

    const float b20 = b2[0], b21 = b2[1];
    float2* __restrict__ out_spk = (float2*)out;
    float2* __restrict__ out_mem = (float2*)(out + (size_t)T * BATCH * NO);

    float m0 = 0.0f, m1 = 0.0f, s0 = 0.0f, s1 = 0.0f;
#pragma unroll
    for (int t = 0; t < T; ++t) {
        const float c0 = acc0[t] + b20;          // cur2 = spk1·W2ᵀ + b2
        const float c1 = acc1[t] + b21;
        m0 = fmaf(BETA, m0, c0) - s0;            // beta*mem2 + cur2 - reset2
        m1 = fmaf(BETA, m1, c1) - s1;
        s0 = (m0 > THR) ? 1.0f : 0.0f;           // spk2
        s1 = (m1 > THR) ? 1.0f : 0.0f;
        // thread b writes pair at element b -> wave writes 512 contiguous bytes
        out_spk[(size_t)t * BATCH + b] = make_float2(s0, s1);
        out_mem[(size_t)t * BATCH + b] = make_float2(m0, m1);
    }
}

extern "C" void kernel_launch(void* const* d_in, const int* in_sizes, int n_in,
                              void* d_out, int out_size, void* d_ws, size_t ws_size,
                              hipStream_t stream) {
    const float* x  = (const float*)d_in[0];
    const float* W1 = (const float*)d_in[1];
    const float* b1 = (const float*)d_in[2];
    const float* W2 = (const float*)d_in[3];
    const float* b2 = (const float*)d_in[4];
    float* out = (float*)d_out;

    dim3 block(256);
    dim3 grid(BATCH / 256);
    snn_fwd<<<grid, block, 0, stream>>>(x, W1, b1, W2, b2, out);
}